// Round 15
// baseline (40.846 us; speedup 1.0000x reference)
//
#include <hip/hip_runtime.h>
#include <math.h>

#define N_NODES 32
#define DIM     128
#define NTHR_H  256
#define HIST_BLOCKS 128
#define NTHR_P  256
#define PACK_BLOCKS 64    // 0..47: GRU weight frags; 48..63: fc1 bf16
#define NTHR_G  512       // 8 waves, 2 waves/SIMD -> 256 VGPR budget

#define SHS 132   // fp32 row stride (elements)
#define SBS 136   // bf16 row stride (elements; 272 B)
#define STS 40    // bf16 transposed stride (80 B)

typedef __attribute__((ext_vector_type(8))) short bf16x8;
typedef __attribute__((ext_vector_type(4))) float f32x4;

// round-to-nearest-even f32 -> bf16 bits (finite values only)
__device__ __forceinline__ unsigned short f2bf(float f) {
  unsigned int u = __float_as_uint(f);
  u += 0x7fffu + ((u >> 16) & 1u);
  return (unsigned short)(u >> 16);
}
__device__ __forceinline__ float bf2f(unsigned short b) {
  return __uint_as_float(((unsigned int)b) << 16);
}

#define LOG2E 1.44269504088896340736f
__device__ __forceinline__ float fexp2(float x) { return __builtin_amdgcn_exp2f(x); }
__device__ __forceinline__ float frcp(float x)  { return __builtin_amdgcn_rcpf(x); }
__device__ __forceinline__ float sigm(float x)  { return frcp(1.f + fexp2(-LOG2E * x)); }
__device__ __forceinline__ float ftanh(float x) { return 1.f - 2.f * frcp(1.f + fexp2((2.f * LOG2E) * x)); }

// ---------------- histogram over edges (index-only, loop-invariant) ---------
__global__ __launch_bounds__(NTHR_H) void hist_kernel(
    const int* __restrict__ es, const int* __restrict__ ed,
    const int* __restrict__ ef, int E,
    int* __restrict__ hA, int* __restrict__ hF)
{
  __shared__ int lA[N_NODES * N_NODES];
  __shared__ int lF[N_NODES * 6];
  const int t = threadIdx.x;
  for (int i = t; i < N_NODES * N_NODES; i += NTHR_H) lA[i] = 0;
  for (int i = t; i < N_NODES * 6;       i += NTHR_H) lF[i] = 0;
  __syncthreads();

  const int E4 = E >> 2;
  const int4* es4 = (const int4*)es;
  const int4* ed4 = (const int4*)ed;
  const int4* ef4 = (const int4*)ef;
  #define DO_EDGE(S, D, F) \
    if ((unsigned)(S) < N_NODES && (unsigned)(D) < N_NODES) { \
      atomicAdd(&lA[(D) * N_NODES + (S)], 1); \
      atomicAdd(&lF[(D) * 6 + (F)], 1); }
  for (int i = blockIdx.x * NTHR_H + t; i < E4; i += gridDim.x * NTHR_H) {
    int4 s4 = es4[i], d4 = ed4[i], f4 = ef4[i];
    DO_EDGE(s4.x, d4.x, f4.x)
    DO_EDGE(s4.y, d4.y, f4.y)
    DO_EDGE(s4.z, d4.z, f4.z)
    DO_EDGE(s4.w, d4.w, f4.w)
  }
  if (blockIdx.x == 0) {
    for (int e = (E4 << 2) + t; e < E; e += NTHR_H) {
      int s = es[e], d = ed[e], f = ef[e];
      DO_EDGE(s, d, f)
    }
  }
  #undef DO_EDGE
  __syncthreads();
  for (int i = t; i < N_NODES * N_NODES; i += NTHR_H) { int v = lA[i]; if (v) atomicAdd(&hA[i], v); }
  for (int i = t; i < N_NODES * 6;       i += NTHR_H) { int v = lF[i]; if (v) atomicAdd(&hF[i], v); }
}

// ------- pack [w_ih;w_hh] -> bf16 fragments, fc1 -> bf16; zero hA/hF --------
// Fragment: lane l holds W[row][k] with row = nt*16 + (l&15),
// k = kt*32 + (l>>4)*8 + j. Same lane map serves as A-frag (D = W @ X^T).
__global__ __launch_bounds__(NTHR_P) void pack_kernel(
    const float* __restrict__ w_ih, const float* __restrict__ w_hh,
    const float* __restrict__ fc1_w,
    unsigned short* __restrict__ pack, unsigned short* __restrict__ packF1,
    int* __restrict__ hA, int* __restrict__ hF)
{
  if (blockIdx.x == 0) {
    for (int i = threadIdx.x; i < N_NODES * N_NODES; i += NTHR_P) hA[i] = 0;
    for (int i = threadIdx.x; i < N_NODES * 6;       i += NTHR_P) hF[i] = 0;
  }
  if (blockIdx.x < 48) {
    const int gid = blockIdx.x * NTHR_P + threadIdx.x;  // 0..12287
    const int T = gid >> 6;          // 0..191
    const int l = gid & 63;
    const int mm = T / 96;           // 0 = w_ih, 1 = w_hh
    const int t2 = T % 96;
    const int nt = t2 >> 2;          // 0..23 row-tile over 384
    const int kt = t2 & 3;
    const int row = nt * 16 + (l & 15);
    const int k   = kt * 32 + (l >> 4) * 8;
    const float* src = (mm ? w_hh : w_ih) + (size_t)row * DIM + k;
    bf16x8 out;
#pragma unroll
    for (int j = 0; j < 8; ++j) out[j] = (short)f2bf(src[j]);
    *(bf16x8*)(pack + (size_t)T * 512 + l * 8) = out;
  } else {
    // fc1_w (128x256 fp32) -> bf16 linear
    const int j = ((blockIdx.x - 48) * NTHR_P + threadIdx.x) * 8;  // 0..32760
    const float4 lo = *(const float4*)(fc1_w + j);
    const float4 hi = *(const float4*)(fc1_w + j + 4);
    bf16x8 v;
    v[0] = (short)f2bf(lo.x); v[1] = (short)f2bf(lo.y);
    v[2] = (short)f2bf(lo.z); v[3] = (short)f2bf(lo.w);
    v[4] = (short)f2bf(hi.x); v[5] = (short)f2bf(hi.y);
    v[6] = (short)f2bf(hi.z); v[7] = (short)f2bf(hi.w);
    *(bf16x8*)(packF1 + j) = v;
  }
}

// --------- single-workgroup GRU, transposed MFMA orientation ----------------
struct GnnParams {
  const int* nt; const int* tr;
  const float* ne_w; const float* te_w; const float* ef_w;
  const float* b_ih; const float* b_hh;
  const float* ln_g; const float* ln_b;
  const float* fc1_b;
  const float* ln2_g; const float* ln2_b;
  const float* fc2_w; const float* fc2_b;
  const int* hA; const int* hF;
  const unsigned short* pack; const unsigned short* packF1;
  float* out;
};

__global__ __launch_bounds__(NTHR_G, 2) void gnn_kernel(GnnParams p)
{
  const int t  = threadIdx.x;
  const int W  = t >> 6;           // wave 0..7 = dim-tile
  const int l  = t & 63;
  const int g  = l >> 4;           // row-group 0..3
  const int li = l & 15;           // node-within-tile / row-within-tile
  const int d0 = W * 16 + g * 4;   // this lane's 4 dims: d0..d0+3

  __shared__ __align__(16) float sh[N_NODES * SHS];        // fp32 h (head only)
  __shared__ __align__(16) float sBnorm[N_NODES * SHS];    // (F@ef_w)/cnt
  __shared__ __align__(16) unsigned short hbf  [N_NODES * SBS]; // bf16 h [node][dim]
  __shared__ __align__(16) unsigned short aggTT[N_NODES * SBS]; // bf16 agg [node][dim]
  __shared__ __align__(16) unsigned short hbT  [DIM * STS];     // bf16 h^T [dim][node]
  __shared__ __align__(16) unsigned short anormP[2 * 64 * 8];   // Anorm frags
  __shared__ __align__(16) float part_s[N_NODES * 8];
  __shared__ __align__(16) float part_q[N_NODES * 8];
  __shared__ __align__(16) int   sAraw[N_NODES * N_NODES];
  __shared__ float sicnt[N_NODES];
  __shared__ int   snt[N_NODES], str[N_NODES], shF[192];
  __shared__ float pooled[2 * DIM], svals[DIM], red[4];

  // ---- issue independent global loads up front ------------------------------
  bf16x8 Bw[6][4];
#pragma unroll
  for (int q = 0; q < 6; ++q)
#pragma unroll
    for (int kt = 0; kt < 4; ++kt) {
      const int T = (q < 3) ? ((q * 8 + W) * 4 + kt)
                            : (96 + ((q - 3) * 8 + W) * 4 + kt);
      Bw[q][kt] = *(const bf16x8*)(p.pack + (size_t)T * 512 + (size_t)l * 8);
    }
  bf16x8 F1[8];
#pragma unroll
  for (int j = 0; j < 8; ++j)
    F1[j] = *(const bf16x8*)(p.packF1 + (size_t)t * 64 + j * 8);

  const f32x4 bir = *(const f32x4*)&p.b_ih[d0];
  const f32x4 biz = *(const f32x4*)&p.b_ih[DIM + d0];
  const f32x4 bin = *(const f32x4*)&p.b_ih[2 * DIM + d0];
  const f32x4 bhr = *(const f32x4*)&p.b_hh[d0];
  const f32x4 bhz = *(const f32x4*)&p.b_hh[DIM + d0];
  const f32x4 bhn = *(const f32x4*)&p.b_hh[2 * DIM + d0];
  const f32x4 lg4 = *(const f32x4*)&p.ln_g[d0];
  const f32x4 lb4 = *(const f32x4*)&p.ln_b[d0];
  const int2  hAv = *(const int2*)(p.hA + t * 2);   // coalesced 1024 ints
  const float fc1b_ = p.fc1_b[t >> 2];
  const float fc2b  = p.fc2_b[0];
  float ln2g_ = 0.f, ln2b_ = 0.f, f2w_ = 0.f;
  if (t < DIM) { ln2g_ = p.ln2_g[t]; ln2b_ = p.ln2_b[t]; f2w_ = p.fc2_w[t]; }

  // ---- small tables ----------------------------------------------------------
  if (t < 32) { snt[t] = p.nt[t]; str[t] = p.tr[t]; }
  if (t < 192) shF[t] = p.hF[t];
  *(int2*)&sAraw[t * 2] = hAv;
  __syncthreads();

  if (t < 32) {
    int c = 0;
#pragma unroll
    for (int s = 0; s < 32; ++s) c += sAraw[t * 32 + s];
    sicnt[t] = 1.0f / fmaxf((float)c, 1.0f);
  }
  __syncthreads();

  // h0 (fp32 + bf16 + transposed) and Bnorm
  for (int i = t; i < N_NODES * DIM; i += NTHR_G) {
    const int n = i >> 7, d2 = i & (DIM - 1);
    const float v = p.ne_w[snt[n] * DIM + d2] + p.te_w[str[n] * DIM + d2];
    sh[n * SHS + d2] = v;
    const unsigned short bv = f2bf(v);
    hbf[n * SBS + d2] = bv;
    hbT[d2 * STS + n] = bv;
    float acc = 0.f;
#pragma unroll
    for (int f = 0; f < 6; ++f)
      acc = fmaf((float)shF[n * 6 + f], p.ef_w[f * DIM + d2], acc);
    sBnorm[n * SHS + d2] = acc * sicnt[n];
  }
  if (t < 128) {   // Anorm fragments (B-operand; same lane map as weights)
    const int mt = t >> 6, ll = t & 63;
    const int m = mt * 16 + (ll & 15);
    const float ic = sicnt[m];
#pragma unroll
    for (int j = 0; j < 8; ++j) {
      const int s = (ll >> 4) * 8 + j;
      anormP[(mt * 64 + ll) * 8 + j] = f2bf((float)sAraw[m * 32 + s] * ic);
    }
  }
  __syncthreads();

  // loop-invariant register caches
  const bf16x8 aN0 = *(const bf16x8*)&anormP[l * 8];         // ntile 0
  const bf16x8 aN1 = *(const bf16x8*)&anormP[(64 + l) * 8];  // ntile 1
  const f32x4 cB0 = *(const f32x4*)&sBnorm[(li)      * SHS + d0];  // Bnorm^T
  const f32x4 cB1 = *(const f32x4*)&sBnorm[(16 + li) * SHS + d0];
  f32x4 hv0 = *(const f32x4*)&sh[(li)      * SHS + d0];      // h in regs
  f32x4 hv1 = *(const f32x4*)&sh[(16 + li) * SHS + d0];
  const f32x4 fz = {0.f, 0.f, 0.f, 0.f};

  // ---------------- 5 GRU iterations ----------------------------------------
  for (int it = 0; it < 5; ++it) {
    // Phase A: agg^T tile (M=16 dims of wave W, N=2x16 nodes, K=32 src)
    {
      const bf16x8 hT = *(const bf16x8*)&hbT[(W * 16 + li) * STS + g * 8];
      const f32x4 dA0 = __builtin_amdgcn_mfma_f32_16x16x32_bf16(hT, aN0, cB0, 0, 0, 0);
      const f32x4 dA1 = __builtin_amdgcn_mfma_f32_16x16x32_bf16(hT, aN1, cB1, 0, 0, 0);
      unsigned long long w0 =
          (unsigned long long)f2bf(dA0[0]) |
          ((unsigned long long)f2bf(dA0[1]) << 16) |
          ((unsigned long long)f2bf(dA0[2]) << 32) |
          ((unsigned long long)f2bf(dA0[3]) << 48);
      unsigned long long w1 =
          (unsigned long long)f2bf(dA1[0]) |
          ((unsigned long long)f2bf(dA1[1]) << 16) |
          ((unsigned long long)f2bf(dA1[2]) << 32) |
          ((unsigned long long)f2bf(dA1[3]) << 48);
      *(unsigned long long*)&aggTT[(li)      * SBS + d0] = w0;
      *(unsigned long long*)&aggTT[(16 + li) * SBS + d0] = w1;
    }
    __syncthreads();   // aggTT ready; prev FIN's hbf visible to all waves

    // Phase B: G^T = W @ X^T (A = weight frags in regs)
    f32x4 Ai[3][2], Hh[3][2];
#pragma unroll
    for (int q = 0; q < 3; ++q) {
      Ai[q][0] = fz; Ai[q][1] = fz; Hh[q][0] = fz; Hh[q][1] = fz;
    }
#pragma unroll
    for (int kt = 0; kt < 4; ++kt) {
      const int ko = kt * 32 + g * 8;
      const bf16x8 xA0 = *(const bf16x8*)&aggTT[(li)      * SBS + ko];
      const bf16x8 xA1 = *(const bf16x8*)&aggTT[(16 + li) * SBS + ko];
      const bf16x8 xH0 = *(const bf16x8*)&hbf  [(li)      * SBS + ko];
      const bf16x8 xH1 = *(const bf16x8*)&hbf  [(16 + li) * SBS + ko];
#pragma unroll
      for (int q = 0; q < 3; ++q) {
        Ai[q][0] = __builtin_amdgcn_mfma_f32_16x16x32_bf16(Bw[q][kt],     xA0, Ai[q][0], 0, 0, 0);
        Ai[q][1] = __builtin_amdgcn_mfma_f32_16x16x32_bf16(Bw[q][kt],     xA1, Ai[q][1], 0, 0, 0);
        Hh[q][0] = __builtin_amdgcn_mfma_f32_16x16x32_bf16(Bw[3 + q][kt], xH0, Hh[q][0], 0, 0, 0);
        Hh[q][1] = __builtin_amdgcn_mfma_f32_16x16x32_bf16(Bw[3 + q][kt], xH1, Hh[q][1], 0, 0, 0);
      }
    }

    // gates (4 dims x 2 nodes per lane) + LN partials (2 shfls per quantity)
    f32x4 hp0, hp1;
#pragma unroll
    for (int j = 0; j < 4; ++j) {
      {
        const float r_ = sigm(Ai[0][0][j] + bir[j] + Hh[0][0][j] + bhr[j]);
        const float z_ = sigm(Ai[1][0][j] + biz[j] + Hh[1][0][j] + bhz[j]);
        const float n_ = ftanh(Ai[2][0][j] + bin[j] + r_ * (Hh[2][0][j] + bhn[j]));
        hp0[j] = (1.f - z_) * n_ + z_ * hv0[j];
      }
      {
        const float r_ = sigm(Ai[0][1][j] + bir[j] + Hh[0][1][j] + bhr[j]);
        const float z_ = sigm(Ai[1][1][j] + biz[j] + Hh[1][1][j] + bhz[j]);
        const float n_ = ftanh(Ai[2][1][j] + bin[j] + r_ * (Hh[2][1][j] + bhn[j]));
        hp1[j] = (1.f - z_) * n_ + z_ * hv1[j];
      }
    }
    {
      float s0 = (hp0[0] + hp0[1]) + (hp0[2] + hp0[3]);
      float q0 = (hp0[0] * hp0[0] + hp0[1] * hp0[1]) + (hp0[2] * hp0[2] + hp0[3] * hp0[3]);
      float s1 = (hp1[0] + hp1[1]) + (hp1[2] + hp1[3]);
      float q1 = (hp1[0] * hp1[0] + hp1[1] * hp1[1]) + (hp1[2] * hp1[2] + hp1[3] * hp1[3]);
      s0 += __shfl_xor(s0, 16); q0 += __shfl_xor(q0, 16);
      s1 += __shfl_xor(s1, 16); q1 += __shfl_xor(q1, 16);
      s0 += __shfl_xor(s0, 32); q0 += __shfl_xor(q0, 32);
      s1 += __shfl_xor(s1, 32); q1 += __shfl_xor(q1, 32);
      if (g == 0) {
        part_s[(li)      * 8 + W] = s0;  part_q[(li)      * 8 + W] = q0;
        part_s[(16 + li) * 8 + W] = s1;  part_q[(16 + li) * 8 + W] = q1;
      }
    }
    __syncthreads();   // partials visible

    // FIN: mean/rstd per node (8 b128 reads) + LN write-back (vector writes)
    #define FIN_NODE(NODE, HP, HV)                                             \
    {                                                                          \
      const f32x4 s0 = *(const f32x4*)&part_s[(NODE) * 8];                     \
      const f32x4 s1 = *(const f32x4*)&part_s[(NODE) * 8 + 4];                 \
      const f32x4 q0 = *(const f32x4*)&part_q[(NODE) * 8];                     \
      const f32x4 q1 = *(const f32x4*)&part_q[(NODE) * 8 + 4];                 \
      const float mean = (((s0[0] + s0[1]) + (s0[2] + s0[3])) +                \
                          ((s1[0] + s1[1]) + (s1[2] + s1[3]))) * (1.0f / DIM); \
      const float var  = (((q0[0] + q0[1]) + (q0[2] + q0[3])) +                \
                          ((q1[0] + q1[1]) + (q1[2] + q1[3]))) * (1.0f / DIM)  \
                         - mean * mean;                                        \
      const float rstd = rsqrtf(var + 1e-5f);                                  \
      _Pragma("unroll")                                                        \
      for (int j = 0; j < 4; ++j)                                              \
        HV[j] = (HP[j] - mean) * rstd * lg4[j] + lb4[j];                       \
      unsigned long long wb =                                                  \
          (unsigned long long)f2bf(HV[0]) |                                    \
          ((unsigned long long)f2bf(HV[1]) << 16) |                            \
          ((unsigned long long)f2bf(HV[2]) << 32) |                            \
          ((unsigned long long)f2bf(HV[3]) << 48);                             \
      *(unsigned long long*)&hbf[(NODE) * SBS + d0] = wb;                      \
      hbT[(d0 + 0) * STS + (NODE)] = (unsigned short)(wb & 0xffff);            \
      hbT[(d0 + 1) * STS + (NODE)] = (unsigned short)((wb >> 16) & 0xffff);    \
      hbT[(d0 + 2) * STS + (NODE)] = (unsigned short)((wb >> 32) & 0xffff);    \
      hbT[(d0 + 3) * STS + (NODE)] = (unsigned short)(wb >> 48);               \
      if (it == 4) *(f32x4*)&sh[(NODE) * SHS + d0] = HV;                       \
    }
    FIN_NODE(li,      hp0, hv0)
    FIN_NODE(16 + li, hp1, hv1)
    #undef FIN_NODE
    // no barrier: next Phase A reads hbT rows of OWN wave's dim-tile only;
    // cross-wave hbf/aggTT consumers are fenced by the Phase-A barrier.
  }
  __syncthreads();   // sh complete for head

  // ---------------- head (zero global loads) ---------------------------------
  if (t < DIM) {
    float s = 0.f, mx = -INFINITY;
#pragma unroll
    for (int n2 = 0; n2 < N_NODES; ++n2) {
      const float v = sh[n2 * SHS + t];
      s += v; mx = fmaxf(mx, v);
    }
    pooled[t]       = s * (1.0f / N_NODES);
    pooled[t + DIM] = mx;
  }
  __syncthreads();

  // fc1 from registers: 4 lanes per output row
  {
    const int part = t & 3;
    float acc = 0.f;
#pragma unroll
    for (int j = 0; j < 8; ++j) {
      const bf16x8 f = F1[j];
#pragma unroll
      for (int e = 0; e < 8; ++e)
        acc = fmaf(bf2f((unsigned short)f[e]), pooled[part * 64 + j * 8 + e], acc);
    }
    acc += __shfl_xor(acc, 1, 4);
    acc += __shfl_xor(acc, 2, 4);
    if (part == 0) svals[t >> 2] = acc + fc1b_;
  }
  __syncthreads();

  if (t < DIM) {
    float s = svals[t];
#pragma unroll
    for (int o = 32; o > 0; o >>= 1) s += __shfl_down(s, o, 64);
    if ((t & 63) == 0) red[t >> 6] = s;
  }
  __syncthreads();
  const float mean2 = (red[0] + red[1]) * (1.0f / DIM);
  if (t < DIM) {
    const float dx = svals[t] - mean2;
    float s = dx * dx;
#pragma unroll
    for (int o = 32; o > 0; o >>= 1) s += __shfl_down(s, o, 64);
    if ((t & 63) == 0) red[2 + (t >> 6)] = s;
  }
  __syncthreads();
  const float var2  = (red[2] + red[3]) * (1.0f / DIM);
  const float rstd2 = rsqrtf(var2 + 1e-5f);
  __syncthreads();
  if (t < DIM) {
    float x = (svals[t] - mean2) * rstd2 * ln2g_ + ln2b_;
    x = fmaxf(x, 0.f);
    float s = x * f2w_;
#pragma unroll
    for (int o = 32; o > 0; o >>= 1) s += __shfl_down(s, o, 64);
    if ((t & 63) == 0) red[t >> 6] = s;
  }
  __syncthreads();
  if (t == 0) p.out[0] = red[0] + red[1] + fc2b;
}

// ---------------------------------------------------------------------------
extern "C" void kernel_launch(void* const* d_in, const int* in_sizes, int n_in,
                              void* d_out, int out_size, void* d_ws, size_t ws_size,
                              hipStream_t stream)
{
  const int*   nt    = (const int*)d_in[0];
  const int*   tr    = (const int*)d_in[1];
  const int*   es    = (const int*)d_in[2];
  const int*   ed    = (const int*)d_in[3];
  const int*   ef    = (const int*)d_in[4];
  const float* ne_w  = (const float*)d_in[5];
  const float* te_w  = (const float*)d_in[6];
  const float* ef_w  = (const float*)d_in[7];
  const float* w_ih  = (const float*)d_in[8];
  const float* w_hh  = (const float*)d_in[9];
  const float* b_ih  = (const float*)d_in[10];
  const float* b_hh  = (const float*)d_in[11];
  const float* ln_g  = (const float*)d_in[12];
  const float* ln_b  = (const float*)d_in[13];
  const float* fc1_w = (const float*)d_in[14];
  const float* fc1_b = (const float*)d_in[15];
  const float* ln2_g = (const float*)d_in[16];
  const float* ln2_b = (const float*)d_in[17];
  const float* fc2_w = (const float*)d_in[18];
  const float* fc2_b = (const float*)d_in[19];

  const int E = in_sizes[2];

  // ws: hA[1024]@0 | hF[192]@4096 | pack@8192 (192K) | packF1@204800 (64K)
  int*            hA     = (int*)d_ws;
  int*            hF     = (int*)((char*)d_ws + 4096);
  unsigned short* pack   = (unsigned short*)((char*)d_ws + 8192);
  unsigned short* packF1 = (unsigned short*)((char*)d_ws + 204800);

  // pack zeroes hA/hF (stream order: pack -> hist -> gnn)
  hipLaunchKernelGGL(pack_kernel, dim3(PACK_BLOCKS), dim3(NTHR_P), 0, stream,
                     w_ih, w_hh, fc1_w, pack, packF1, hA, hF);
  hipLaunchKernelGGL(hist_kernel, dim3(HIST_BLOCKS), dim3(NTHR_H), 0, stream,
                     es, ed, ef, E, hA, hF);

  GnnParams prm;
  prm.nt = nt; prm.tr = tr;
  prm.ne_w = ne_w; prm.te_w = te_w; prm.ef_w = ef_w;
  prm.b_ih = b_ih; prm.b_hh = b_hh;
  prm.ln_g = ln_g; prm.ln_b = ln_b;
  prm.fc1_b = fc1_b;
  prm.ln2_g = ln2_g; prm.ln2_b = ln2_b;
  prm.fc2_w = fc2_w; prm.fc2_b = fc2_b;
  prm.hA = hA; prm.hF = hF; prm.pack = pack; prm.packF1 = packF1;
  prm.out = (float*)d_out;

  hipLaunchKernelGGL(gnn_kernel, dim3(1), dim3(NTHR_G), 0, stream, prm);
}

// Round 16
// 36.347 us; speedup vs baseline: 1.1238x; 1.1238x over previous
//
#include <hip/hip_runtime.h>
#include <math.h>

#define N_NODES 32
#define DIM     128
#define NTHR    512        // one block size for the mega kernel (8 waves)
#define HIST_NBLK 64       // blocks 1..64
#define PACK_NBLK 24       // blocks 65..88
#define NBLK_TOTAL (1 + HIST_NBLK + PACK_NBLK)

#define SHS 132   // fp32 row stride (elements)
#define SBS 136   // bf16 row stride (elements; 272 B)
#define STS 40    // bf16 transposed stride (80 B)

typedef __attribute__((ext_vector_type(8))) short bf16x8;
typedef __attribute__((ext_vector_type(4))) float f32x4;

// round-to-nearest-even f32 -> bf16 bits (finite values only)
__device__ __forceinline__ unsigned short f2bf(float f) {
  unsigned int u = __float_as_uint(f);
  u += 0x7fffu + ((u >> 16) & 1u);
  return (unsigned short)(u >> 16);
}

#define LOG2E 1.44269504088896340736f
__device__ __forceinline__ float fexp2(float x) { return __builtin_amdgcn_exp2f(x); }
__device__ __forceinline__ float frcp(float x)  { return __builtin_amdgcn_rcpf(x); }
__device__ __forceinline__ float sigm(float x)  { return frcp(1.f + fexp2(-LOG2E * x)); }
__device__ __forceinline__ float ftanh(float x) { return 1.f - 2.f * frcp(1.f + fexp2((2.f * LOG2E) * x)); }

// ---- agent-scope (MALL-coherent) helpers: validated pattern from R5-R7 -----
__device__ __forceinline__ void st8_sc1(unsigned long long* p, unsigned long long v) {
  __hip_atomic_store(p, v, __ATOMIC_RELAXED, __HIP_MEMORY_SCOPE_AGENT);
}
__device__ __forceinline__ unsigned long long ld8_sc1(const unsigned long long* p) {
  return __hip_atomic_load(p, __ATOMIC_RELAXED, __HIP_MEMORY_SCOPE_AGENT);
}
__device__ __forceinline__ int ld4_sc1(const int* p) {
  return __hip_atomic_load(p, __ATOMIC_RELAXED, __HIP_MEMORY_SCOPE_AGENT);
}
__device__ __forceinline__ void wait_flag(const int* f, int target) {
  if (threadIdx.x == 0) {
    while (__hip_atomic_load(f, __ATOMIC_ACQUIRE, __HIP_MEMORY_SCOPE_AGENT) != target)
      __builtin_amdgcn_s_sleep(1);
  }
  __syncthreads();
}
__device__ __forceinline__ void bump_flag(int* f) {
  __syncthreads();   // all prior LDS/global ops of the block complete
  if (threadIdx.x == 0)
    __hip_atomic_fetch_add(f, 1, __ATOMIC_RELEASE, __HIP_MEMORY_SCOPE_AGENT);
}
__device__ __forceinline__ bf16x8 ld_frag_sc1(const unsigned short* pp) {
  union { unsigned long long u[2]; bf16x8 v; } x;
  x.u[0] = ld8_sc1((const unsigned long long*)pp);
  x.u[1] = ld8_sc1((const unsigned long long*)(pp + 4));
  return x.v;
}

// ---------------- mega kernel: block 0 = GRU, 1..64 = hist, 65..88 = pack ---
struct MegaParams {
  // edges
  const int* es; const int* ed; const int* ef; int E;
  // weights
  const float* w_ih; const float* w_hh;
  // gnn params
  const int* nt; const int* tr;
  const float* ne_w; const float* te_w; const float* ef_w;
  const float* b_ih; const float* b_hh;
  const float* ln_g; const float* ln_b;
  const float* fc1_w; const float* fc1_b;
  const float* ln2_g; const float* ln2_b;
  const float* fc2_w; const float* fc2_b;
  // workspace
  int* hA; int* hF; int* flags;          // flags[0]=hist, flags[1]=pack
  unsigned short* pack;
  float* out;
};

__global__ __launch_bounds__(NTHR, 2) void mega_kernel(MegaParams p)
{
  const int b = blockIdx.x;
  const int t = threadIdx.x;

  // =================== hist blocks (1..64) ==================================
  if (b >= 1 && b <= HIST_NBLK) {
    __shared__ int lA[N_NODES * N_NODES];
    __shared__ int lF[N_NODES * 6];
    for (int i = t; i < N_NODES * N_NODES; i += NTHR) lA[i] = 0;
    for (int i = t; i < N_NODES * 6;       i += NTHR) lF[i] = 0;
    __syncthreads();

    const int b2 = b - 1;
    const int E4 = p.E >> 2;
    const int4* es4 = (const int4*)p.es;
    const int4* ed4 = (const int4*)p.ed;
    const int4* ef4 = (const int4*)p.ef;
    #define DO_EDGE(S, D, F) \
      if ((unsigned)(S) < N_NODES && (unsigned)(D) < N_NODES) { \
        atomicAdd(&lA[(D) * N_NODES + (S)], 1); \
        atomicAdd(&lF[(D) * 6 + (F)], 1); }
    for (int i = b2 * NTHR + t; i < E4; i += HIST_NBLK * NTHR) {
      int4 s4 = es4[i], d4 = ed4[i], f4 = ef4[i];
      DO_EDGE(s4.x, d4.x, f4.x)
      DO_EDGE(s4.y, d4.y, f4.y)
      DO_EDGE(s4.z, d4.z, f4.z)
      DO_EDGE(s4.w, d4.w, f4.w)
    }
    if (b2 == 0) {
      for (int e = (E4 << 2) + t; e < p.E; e += NTHR) {
        int s = p.es[e], d = p.ed[e], f = p.ef[e];
        DO_EDGE(s, d, f)
      }
    }
    #undef DO_EDGE
    __syncthreads();
    for (int i = t; i < N_NODES * N_NODES; i += NTHR) { int v = lA[i]; if (v) atomicAdd(&p.hA[i], v); }
    for (int i = t; i < N_NODES * 6;       i += NTHR) { int v = lF[i]; if (v) atomicAdd(&p.hF[i], v); }
    bump_flag(&p.flags[0]);
    return;
  }

  // =================== pack blocks (65..88) =================================
  if (b > HIST_NBLK) {
    // Fragment: lane l holds W[row][k], row = nt*16+(l&15), k = kt*32+(l>>4)*8+j
    const int gid = (b - HIST_NBLK - 1) * NTHR + t;   // 0..12287
    const int T = gid >> 6;          // 0..191
    const int l = gid & 63;
    const int mm = T / 96;           // 0 = w_ih, 1 = w_hh
    const int t2 = T % 96;
    const int nt2 = t2 >> 2;         // 0..23 row-tile over 384
    const int kt = t2 & 3;
    const int row = nt2 * 16 + (l & 15);
    const int k   = kt * 32 + (l >> 4) * 8;
    const float* src = (mm ? p.w_hh : p.w_ih) + (size_t)row * DIM + k;
    union { unsigned long long u[2]; unsigned short s[8]; } out;
#pragma unroll
    for (int j = 0; j < 8; ++j) out.s[j] = f2bf(src[j]);
    unsigned long long* dst = (unsigned long long*)(p.pack + (size_t)T * 512 + l * 8);
    st8_sc1(dst,     out.u[0]);   // MALL-coherent: visible to block 0 cross-XCD
    st8_sc1(dst + 1, out.u[1]);
    bump_flag(&p.flags[1]);
    return;
  }

  // =================== block 0: single-workgroup GRU ========================
  const int W  = t >> 6;           // wave 0..7 = dim-tile
  const int l  = t & 63;
  const int g  = l >> 4;           // row-group 0..3
  const int li = l & 15;           // node-within-tile
  const int d0 = W * 16 + g * 4;   // this lane's 4 dims

  __shared__ __align__(16) float sh[N_NODES * SHS];
  __shared__ __align__(16) float sBnorm[N_NODES * SHS];
  __shared__ __align__(16) unsigned short hbf  [N_NODES * SBS];
  __shared__ __align__(16) unsigned short aggTT[N_NODES * SBS];
  __shared__ __align__(16) unsigned short hbT  [DIM * STS];
  __shared__ __align__(16) unsigned short anormP[2 * 64 * 8];
  __shared__ __align__(16) float part_s[N_NODES * 8];
  __shared__ __align__(16) float part_q[N_NODES * 8];
  __shared__ __align__(16) int   sAraw[N_NODES * N_NODES];
  __shared__ float sicnt[N_NODES];
  __shared__ int   snt[N_NODES], str[N_NODES], shF[192];
  __shared__ float pooled[2 * DIM], svals[DIM], red[4];

  // ---- hist/pack-independent work first (overlaps producers) ---------------
  const f32x4 bir = *(const f32x4*)&p.b_ih[d0];
  const f32x4 biz = *(const f32x4*)&p.b_ih[DIM + d0];
  const f32x4 bin = *(const f32x4*)&p.b_ih[2 * DIM + d0];
  const f32x4 bhr = *(const f32x4*)&p.b_hh[d0];
  const f32x4 bhz = *(const f32x4*)&p.b_hh[DIM + d0];
  const f32x4 bhn = *(const f32x4*)&p.b_hh[2 * DIM + d0];
  const f32x4 lg4 = *(const f32x4*)&p.ln_g[d0];
  const f32x4 lb4 = *(const f32x4*)&p.ln_b[d0];

  if (t < 32) { snt[t] = p.nt[t]; str[t] = p.tr[t]; }
  __syncthreads();

  // h0 staging (fp32 + bf16 + transposed) — no hist/pack dependency
  for (int i = t; i < N_NODES * DIM; i += NTHR) {
    const int n = i >> 7, d2 = i & (DIM - 1);
    const float v = p.ne_w[snt[n] * DIM + d2] + p.te_w[str[n] * DIM + d2];
    sh[n * SHS + d2] = v;
    const unsigned short bv = f2bf(v);
    hbf[n * SBS + d2] = bv;
    hbT[d2 * STS + n] = bv;
  }

  // ---- wait for pack, then load weight fragments (MALL-coherent loads) -----
  wait_flag(&p.flags[1], PACK_NBLK);
  bf16x8 Bw[6][4];
#pragma unroll
  for (int q = 0; q < 6; ++q)
#pragma unroll
    for (int kt = 0; kt < 4; ++kt) {
      const int T = (q < 3) ? ((q * 8 + W) * 4 + kt)
                            : (96 + ((q - 3) * 8 + W) * 4 + kt);
      Bw[q][kt] = ld_frag_sc1(p.pack + (size_t)T * 512 + (size_t)l * 8);
    }

  // ---- wait for hist, then hA/hF-dependent init ----------------------------
  wait_flag(&p.flags[0], HIST_NBLK);
  {
    const unsigned long long v = ld8_sc1((const unsigned long long*)p.hA + t);
    *(unsigned long long*)&sAraw[t * 2] = v;
  }
  if (t < 192) shF[t] = ld4_sc1(&p.hF[t]);
  __syncthreads();

  if (t < 32) {
    int c = 0;
#pragma unroll
    for (int s = 0; s < 32; ++s) c += sAraw[t * 32 + s];
    sicnt[t] = 1.0f / fmaxf((float)c, 1.0f);
  }
  __syncthreads();

  for (int i = t; i < N_NODES * DIM; i += NTHR) {   // Bnorm
    const int n = i >> 7, d2 = i & (DIM - 1);
    float acc = 0.f;
#pragma unroll
    for (int f = 0; f < 6; ++f)
      acc = fmaf((float)shF[n * 6 + f], p.ef_w[f * DIM + d2], acc);
    sBnorm[n * SHS + d2] = acc * sicnt[n];
  }
  if (t < 128) {   // Anorm fragments (B-operand; same lane map as weights)
    const int mt = t >> 6, ll = t & 63;
    const int m = mt * 16 + (ll & 15);
    const float ic = sicnt[m];
#pragma unroll
    for (int j = 0; j < 8; ++j) {
      const int s = (ll >> 4) * 8 + j;
      anormP[(mt * 64 + ll) * 8 + j] = f2bf((float)sAraw[m * 32 + s] * ic);
    }
  }
  __syncthreads();

  // loop-invariant register caches
  const bf16x8 aN0 = *(const bf16x8*)&anormP[l * 8];
  const bf16x8 aN1 = *(const bf16x8*)&anormP[(64 + l) * 8];
  const f32x4 cB0 = *(const f32x4*)&sBnorm[(li)      * SHS + d0];
  const f32x4 cB1 = *(const f32x4*)&sBnorm[(16 + li) * SHS + d0];
  f32x4 hv0 = *(const f32x4*)&sh[(li)      * SHS + d0];
  f32x4 hv1 = *(const f32x4*)&sh[(16 + li) * SHS + d0];
  const f32x4 fz = {0.f, 0.f, 0.f, 0.f};

  // ---------------- 5 GRU iterations (identical to the 37.5 us kernel) ------
  for (int it = 0; it < 5; ++it) {
    // Phase A: agg^T tile
    {
      const bf16x8 hT = *(const bf16x8*)&hbT[(W * 16 + li) * STS + g * 8];
      const f32x4 dA0 = __builtin_amdgcn_mfma_f32_16x16x32_bf16(hT, aN0, cB0, 0, 0, 0);
      const f32x4 dA1 = __builtin_amdgcn_mfma_f32_16x16x32_bf16(hT, aN1, cB1, 0, 0, 0);
      unsigned long long w0 =
          (unsigned long long)f2bf(dA0[0]) |
          ((unsigned long long)f2bf(dA0[1]) << 16) |
          ((unsigned long long)f2bf(dA0[2]) << 32) |
          ((unsigned long long)f2bf(dA0[3]) << 48);
      unsigned long long w1 =
          (unsigned long long)f2bf(dA1[0]) |
          ((unsigned long long)f2bf(dA1[1]) << 16) |
          ((unsigned long long)f2bf(dA1[2]) << 32) |
          ((unsigned long long)f2bf(dA1[3]) << 48);
      *(unsigned long long*)&aggTT[(li)      * SBS + d0] = w0;
      *(unsigned long long*)&aggTT[(16 + li) * SBS + d0] = w1;
    }
    __syncthreads();

    // Phase B: G^T = W @ X^T
    f32x4 Ai[3][2], Hh[3][2];
#pragma unroll
    for (int q = 0; q < 3; ++q) {
      Ai[q][0] = fz; Ai[q][1] = fz; Hh[q][0] = fz; Hh[q][1] = fz;
    }
#pragma unroll
    for (int kt = 0; kt < 4; ++kt) {
      const int ko = kt * 32 + g * 8;
      const bf16x8 xA0 = *(const bf16x8*)&aggTT[(li)      * SBS + ko];
      const bf16x8 xA1 = *(const bf16x8*)&aggTT[(16 + li) * SBS + ko];
      const bf16x8 xH0 = *(const bf16x8*)&hbf  [(li)      * SBS + ko];
      const bf16x8 xH1 = *(const bf16x8*)&hbf  [(16 + li) * SBS + ko];
#pragma unroll
      for (int q = 0; q < 3; ++q) {
        Ai[q][0] = __builtin_amdgcn_mfma_f32_16x16x32_bf16(Bw[q][kt],     xA0, Ai[q][0], 0, 0, 0);
        Ai[q][1] = __builtin_amdgcn_mfma_f32_16x16x32_bf16(Bw[q][kt],     xA1, Ai[q][1], 0, 0, 0);
        Hh[q][0] = __builtin_amdgcn_mfma_f32_16x16x32_bf16(Bw[3 + q][kt], xH0, Hh[q][0], 0, 0, 0);
        Hh[q][1] = __builtin_amdgcn_mfma_f32_16x16x32_bf16(Bw[3 + q][kt], xH1, Hh[q][1], 0, 0, 0);
      }
    }

    // gates + LN partials
    f32x4 hp0, hp1;
#pragma unroll
    for (int j = 0; j < 4; ++j) {
      {
        const float r_ = sigm(Ai[0][0][j] + bir[j] + Hh[0][0][j] + bhr[j]);
        const float z_ = sigm(Ai[1][0][j] + biz[j] + Hh[1][0][j] + bhz[j]);
        const float n_ = ftanh(Ai[2][0][j] + bin[j] + r_ * (Hh[2][0][j] + bhn[j]));
        hp0[j] = (1.f - z_) * n_ + z_ * hv0[j];
      }
      {
        const float r_ = sigm(Ai[0][1][j] + bir[j] + Hh[0][1][j] + bhr[j]);
        const float z_ = sigm(Ai[1][1][j] + biz[j] + Hh[1][1][j] + bhz[j]);
        const float n_ = ftanh(Ai[2][1][j] + bin[j] + r_ * (Hh[2][1][j] + bhn[j]));
        hp1[j] = (1.f - z_) * n_ + z_ * hv1[j];
      }
    }
    {
      float s0 = (hp0[0] + hp0[1]) + (hp0[2] + hp0[3]);
      float q0 = (hp0[0] * hp0[0] + hp0[1] * hp0[1]) + (hp0[2] * hp0[2] + hp0[3] * hp0[3]);
      float s1 = (hp1[0] + hp1[1]) + (hp1[2] + hp1[3]);
      float q1 = (hp1[0] * hp1[0] + hp1[1] * hp1[1]) + (hp1[2] * hp1[2] + hp1[3] * hp1[3]);
      s0 += __shfl_xor(s0, 16); q0 += __shfl_xor(q0, 16);
      s1 += __shfl_xor(s1, 16); q1 += __shfl_xor(q1, 16);
      s0 += __shfl_xor(s0, 32); q0 += __shfl_xor(q0, 32);
      s1 += __shfl_xor(s1, 32); q1 += __shfl_xor(q1, 32);
      if (g == 0) {
        part_s[(li)      * 8 + W] = s0;  part_q[(li)      * 8 + W] = q0;
        part_s[(16 + li) * 8 + W] = s1;  part_q[(16 + li) * 8 + W] = q1;
      }
    }
    __syncthreads();

    // FIN: mean/rstd + LN write-back
    #define FIN_NODE(NODE, HP, HV)                                             \
    {                                                                          \
      const f32x4 s0 = *(const f32x4*)&part_s[(NODE) * 8];                     \
      const f32x4 s1 = *(const f32x4*)&part_s[(NODE) * 8 + 4];                 \
      const f32x4 q0 = *(const f32x4*)&part_q[(NODE) * 8];                     \
      const f32x4 q1 = *(const f32x4*)&part_q[(NODE) * 8 + 4];                 \
      const float mean = (((s0[0] + s0[1]) + (s0[2] + s0[3])) +                \
                          ((s1[0] + s1[1]) + (s1[2] + s1[3]))) * (1.0f / DIM); \
      const float var  = (((q0[0] + q0[1]) + (q0[2] + q0[3])) +                \
                          ((q1[0] + q1[1]) + (q1[2] + q1[3]))) * (1.0f / DIM)  \
                         - mean * mean;                                        \
      const float rstd = rsqrtf(var + 1e-5f);                                  \
      _Pragma("unroll")                                                        \
      for (int j = 0; j < 4; ++j)                                              \
        HV[j] = (HP[j] - mean) * rstd * lg4[j] + lb4[j];                       \
      unsigned long long wb =                                                  \
          (unsigned long long)f2bf(HV[0]) |                                    \
          ((unsigned long long)f2bf(HV[1]) << 16) |                            \
          ((unsigned long long)f2bf(HV[2]) << 32) |                            \
          ((unsigned long long)f2bf(HV[3]) << 48);                             \
      *(unsigned long long*)&hbf[(NODE) * SBS + d0] = wb;                      \
      hbT[(d0 + 0) * STS + (NODE)] = (unsigned short)(wb & 0xffff);            \
      hbT[(d0 + 1) * STS + (NODE)] = (unsigned short)((wb >> 16) & 0xffff);    \
      hbT[(d0 + 2) * STS + (NODE)] = (unsigned short)((wb >> 32) & 0xffff);    \
      hbT[(d0 + 3) * STS + (NODE)] = (unsigned short)(wb >> 48);               \
      *(f32x4*)&sh[(NODE) * SHS + d0] = HV;                                    \
    }
    FIN_NODE(li,      hp0, hv0)
    FIN_NODE(16 + li, hp1, hv1)
    #undef FIN_NODE
    // no barrier: next Phase A reads hbT rows of OWN wave's dim-tile only;
    // cross-wave hbf/aggTT consumers are fenced by the Phase-A barrier.
  }
  __syncthreads();

  // ---------------- head -----------------------------------------------------
  if (t < DIM) {
    float s = 0.f, mx = -INFINITY;
#pragma unroll
    for (int n2 = 0; n2 < N_NODES; ++n2) {
      const float v = sh[n2 * SHS + t];
      s += v; mx = fmaxf(mx, v);
    }
    pooled[t]       = s * (1.0f / N_NODES);
    pooled[t + DIM] = mx;
  }
  __syncthreads();

  // fc1: 4 threads per output row (global fp32 weights)
  {
    const int row = t >> 2, part = t & 3;
    const float4* w4f = (const float4*)(p.fc1_w + (size_t)row * 2 * DIM + part * 64);
    const float4* p4  = (const float4*)(pooled + part * 64);
    float acc = 0.f;
#pragma unroll
    for (int k = 0; k < 16; ++k) {
      const float4 wv = w4f[k]; const float4 pv = p4[k];
      acc = fmaf(wv.x, pv.x, acc);
      acc = fmaf(wv.y, pv.y, acc);
      acc = fmaf(wv.z, pv.z, acc);
      acc = fmaf(wv.w, pv.w, acc);
    }
    acc += __shfl_xor(acc, 1);
    acc += __shfl_xor(acc, 2);
    if (part == 0) svals[row] = acc + p.fc1_b[row];
  }
  __syncthreads();

  if (t < DIM) {
    float s = svals[t];
#pragma unroll
    for (int o = 32; o > 0; o >>= 1) s += __shfl_down(s, o, 64);
    if ((t & 63) == 0) red[t >> 6] = s;
  }
  __syncthreads();
  const float mean2 = (red[0] + red[1]) * (1.0f / DIM);
  if (t < DIM) {
    const float dx = svals[t] - mean2;
    float s = dx * dx;
#pragma unroll
    for (int o = 32; o > 0; o >>= 1) s += __shfl_down(s, o, 64);
    if ((t & 63) == 0) red[2 + (t >> 6)] = s;
  }
  __syncthreads();
  const float var2  = (red[2] + red[3]) * (1.0f / DIM);
  const float rstd2 = rsqrtf(var2 + 1e-5f);
  __syncthreads();
  if (t < DIM) {
    float x = (svals[t] - mean2) * rstd2 * p.ln2_g[t] + p.ln2_b[t];
    x = fmaxf(x, 0.f);
    float s = x * p.fc2_w[t];
#pragma unroll
    for (int o = 32; o > 0; o >>= 1) s += __shfl_down(s, o, 64);
    if ((t & 63) == 0) red[t >> 6] = s;
  }
  __syncthreads();
  if (t == 0) p.out[0] = red[0] + red[1] + p.fc2_b[0];
}

// ---------------------------------------------------------------------------
extern "C" void kernel_launch(void* const* d_in, const int* in_sizes, int n_in,
                              void* d_out, int out_size, void* d_ws, size_t ws_size,
                              hipStream_t stream)
{
  const int*   nt    = (const int*)d_in[0];
  const int*   tr    = (const int*)d_in[1];
  const int*   es    = (const int*)d_in[2];
  const int*   ed    = (const int*)d_in[3];
  const int*   ef    = (const int*)d_in[4];
  const float* ne_w  = (const float*)d_in[5];
  const float* te_w  = (const float*)d_in[6];
  const float* ef_w  = (const float*)d_in[7];
  const float* w_ih  = (const float*)d_in[8];
  const float* w_hh  = (const float*)d_in[9];
  const float* b_ih  = (const float*)d_in[10];
  const float* b_hh  = (const float*)d_in[11];
  const float* ln_g  = (const float*)d_in[12];
  const float* ln_b  = (const float*)d_in[13];
  const float* fc1_w = (const float*)d_in[14];
  const float* fc1_b = (const float*)d_in[15];
  const float* ln2_g = (const float*)d_in[16];
  const float* ln2_b = (const float*)d_in[17];
  const float* fc2_w = (const float*)d_in[18];
  const float* fc2_b = (const float*)d_in[19];

  const int E = in_sizes[2];

  // ws: hA[1024]@0 | hF[192]@4096 | flags[2]@4992 | pack@8192 (192K)
  int*            hA    = (int*)d_ws;
  int*            hF    = (int*)((char*)d_ws + 4096);
  int*            flags = (int*)((char*)d_ws + 4992);
  unsigned short* pack  = (unsigned short*)((char*)d_ws + 8192);

  hipMemsetAsync(d_ws, 0, 5120, stream);   // hA, hF, flags

  MegaParams mp;
  mp.es = es; mp.ed = ed; mp.ef = ef; mp.E = E;
  mp.w_ih = w_ih; mp.w_hh = w_hh;
  mp.nt = nt; mp.tr = tr;
  mp.ne_w = ne_w; mp.te_w = te_w; mp.ef_w = ef_w;
  mp.b_ih = b_ih; mp.b_hh = b_hh;
  mp.ln_g = ln_g; mp.ln_b = ln_b;
  mp.fc1_w = fc1_w; mp.fc1_b = fc1_b;
  mp.ln2_g = ln2_g; mp.ln2_b = ln2_b;
  mp.fc2_w = fc2_w; mp.fc2_b = fc2_b;
  mp.hA = hA; mp.hF = hF; mp.flags = flags; mp.pack = pack;
  mp.out = (float*)d_out;

  hipLaunchKernelGGL(mega_kernel, dim3(NBLK_TOTAL), dim3(NTHR), 0, stream, mp);
}